// Round 2
// baseline (4047.635 us; speedup 1.0000x reference)
//
#include <hip/hip_runtime.h>
#include <math.h>

typedef __bf16 bf16_t;
typedef __bf16 bf16x4 __attribute__((ext_vector_type(4)));
typedef __bf16 bf16x8 __attribute__((ext_vector_type(8)));
typedef float f32x4 __attribute__((ext_vector_type(4)));

#define GLDS(gp, lp) __builtin_amdgcn_global_load_lds( \
    (const __attribute__((address_space(1))) void*)(gp), \
    (__attribute__((address_space(3))) void*)(lp), 16, 0, 0)

static constexpr int B_    = 2;
static constexpr int T_    = 16;
static constexpr int HW_   = 576;
static constexpr int NH_   = 16;
static constexpr int TOK_  = B_ * T_ * HW_;   // 18432
static constexpr int D_    = 1024;
static constexpr int D3_   = 3072;

// ---------------------------------------------------------------------------
// fp32 -> bf16 elementwise convert (vectorized)
// ---------------------------------------------------------------------------
__global__ __launch_bounds__(256) void f2b(const float* __restrict__ in,
                                           bf16_t* __restrict__ out, long n)
{
    for (long i = ((long)blockIdx.x * 256 + threadIdx.x) * 4; i < n;
         i += (long)gridDim.x * 1024) {
        float4 v = *(const float4*)(in + i);
        bf16x4 o;
        o[0] = (bf16_t)v.x; o[1] = (bf16_t)v.y;
        o[2] = (bf16_t)v.z; o[3] = (bf16_t)v.w;
        *(bf16x4*)(out + i) = o;
    }
}

// ---------------------------------------------------------------------------
// Weight transpose + convert: out[N][K](bf16) = in[K][N](fp32), R=K, C=N
// ---------------------------------------------------------------------------
__global__ __launch_bounds__(256) void transpose_k(const float* __restrict__ in,
                                                   bf16_t* __restrict__ out,
                                                   int R, int C)
{
    __shared__ bf16_t tile[32][33];
    const int cb = blockIdx.x * 32, rb = blockIdx.y * 32;
    const int tx = threadIdx.x, ty = threadIdx.y;  // 32 x 8
    #pragma unroll
    for (int i = 0; i < 32; i += 8)
        tile[ty + i][tx] = (bf16_t)in[(long)(rb + ty + i) * C + cb + tx];
    __syncthreads();
    #pragma unroll
    for (int i = 0; i < 32; i += 8)
        out[(long)(cb + ty + i) * R + rb + tx] = tile[tx][ty + i];
}

// ---------------------------------------------------------------------------
// GEMM: C = A[M][K](bf16) * BT[N][K](bf16)^T + bias[N](f32) (+ res[M][N](f32))
// outputs: Cb (bf16, optional) and/or Cf (f32, optional). fp32 accum.
// 128x128 tile, BK=32, 4 waves, 16x16x32 MFMA (m97 structure).
// ---------------------------------------------------------------------------
__global__ __launch_bounds__(256) void gemm_bt(const bf16_t* __restrict__ A,
                                               const bf16_t* __restrict__ BT,
                                               const float* __restrict__ bias,
                                               const float* __restrict__ res,
                                               bf16_t* __restrict__ Cb,
                                               float* __restrict__ Cf,
                                               int M, int N, int K)
{
    __shared__ bf16_t As[128 * 32];
    __shared__ bf16_t Bs[128 * 32];
    const int tid  = threadIdx.x;
    const int lane = tid & 63, wid = tid >> 6;
    const int wr   = wid >> 1, wc = wid & 1;
    const long row0 = (long)blockIdx.y * 128;
    const long col0 = (long)blockIdx.x * 128;
    const int  sr   = tid >> 2;        // 0..63
    const int  sc   = (tid & 3) * 8;   // 0,8,16,24
    const bf16_t* Ag = A  + (row0 + sr) * (long)K + sc;
    const bf16_t* Bg = BT + (col0 + sr) * (long)K + sc;

    f32x4 acc[4][4] = {};

    for (int k0 = 0; k0 < K; k0 += 32) {
        GLDS(Ag + k0,                &As[tid * 8]);
        GLDS(Ag + 64 * (long)K + k0, &As[2048 + tid * 8]);
        GLDS(Bg + k0,                &Bs[tid * 8]);
        GLDS(Bg + 64 * (long)K + k0, &Bs[2048 + tid * 8]);
        __syncthreads();

        bf16x8 a[4], b[4];
        #pragma unroll
        for (int i = 0; i < 4; i++)
            a[i] = *(const bf16x8*)&As[(wr * 64 + i * 16 + (lane & 15)) * 32 + (lane >> 4) * 8];
        #pragma unroll
        for (int j = 0; j < 4; j++)
            b[j] = *(const bf16x8*)&Bs[(wc * 64 + j * 16 + (lane & 15)) * 32 + (lane >> 4) * 8];
        #pragma unroll
        for (int i = 0; i < 4; i++)
            #pragma unroll
            for (int j = 0; j < 4; j++)
                acc[i][j] = __builtin_amdgcn_mfma_f32_16x16x32_bf16(a[i], b[j], acc[i][j], 0, 0, 0);
        __syncthreads();
    }

    // epilogue: C/D frag mapping col=lane&15, row=(lane>>4)*4+reg  [m89]
    #pragma unroll
    for (int i = 0; i < 4; i++) {
        #pragma unroll
        for (int j = 0; j < 4; j++) {
            #pragma unroll
            for (int r = 0; r < 4; r++) {
                const long row = row0 + wr * 64 + i * 16 + ((lane >> 4) * 4 + r);
                const long col = col0 + wc * 64 + j * 16 + (lane & 15);
                float v = acc[i][j][r] + bias[col];
                if (res) v += res[row * (long)N + col];
                if (Cf)  Cf[row * (long)N + col] = v;
                if (Cb)  Cb[row * (long)N + col] = (bf16_t)v;
            }
        }
    }
}

// ---------------------------------------------------------------------------
// Spatial attention: groups (b,t,h), 576 tokens, no mask. 4 queries per wave.
// qkv row layout: [q(1024) k(1024) v(1024)], bf16.
// ---------------------------------------------------------------------------
__global__ __launch_bounds__(256) void attn_spatial(const bf16_t* __restrict__ qkv,
                                                    bf16_t* __restrict__ out)
{
    __shared__ float q_lds[4][4][64];
    __shared__ float p_lds[4][4][576];
    const int tid = threadIdx.x, lane = tid & 63, wid = tid >> 6;
    const int gid   = blockIdx.x;          // 512 groups * 36 chunks
    const int group = gid / 36;
    const int chunk = gid % 36;
    const int h  = group % NH_;
    const int bt = group / NH_;            // 0..31
    const long base = (long)bt * HW_;
    const int r0 = chunk * 16 + wid * 4;   // first of 4 query rows

    #pragma unroll
    for (int qi = 0; qi < 4; qi++)
        q_lds[wid][qi][lane] = 0.125f * (float)qkv[(base + r0 + qi) * D3_ + h * 64 + lane];
    __syncthreads();

    float s[4][9];
    #pragma unroll
    for (int qi = 0; qi < 4; qi++)
        #pragma unroll
        for (int c = 0; c < 9; c++) s[qi][c] = 0.f;

    for (int c = 0; c < 9; c++) {
        const bf16_t* kp = qkv + (base + c * 64 + lane) * D3_ + 1024 + h * 64;
        #pragma unroll
        for (int d0 = 0; d0 < 8; d0++) {
            bf16x8 kv = *(const bf16x8*)(kp + d0 * 8);
            #pragma unroll
            for (int dd = 0; dd < 8; dd++) {
                const float kf = (float)kv[dd];
                #pragma unroll
                for (int qi = 0; qi < 4; qi++)
                    s[qi][c] += q_lds[wid][qi][d0 * 8 + dd] * kf;
            }
        }
    }

    #pragma unroll
    for (int qi = 0; qi < 4; qi++) {
        float m = s[qi][0];
        #pragma unroll
        for (int c = 1; c < 9; c++) m = fmaxf(m, s[qi][c]);
        #pragma unroll
        for (int off = 32; off; off >>= 1) m = fmaxf(m, __shfl_xor(m, off));
        float lsum = 0.f;
        #pragma unroll
        for (int c = 0; c < 9; c++) { s[qi][c] = __expf(s[qi][c] - m); lsum += s[qi][c]; }
        #pragma unroll
        for (int off = 32; off; off >>= 1) lsum += __shfl_xor(lsum, off);
        const float inv = 1.f / lsum;
        #pragma unroll
        for (int c = 0; c < 9; c++) p_lds[wid][qi][c * 64 + lane] = s[qi][c] * inv;
    }
    __syncthreads();

    float o[4] = {0.f, 0.f, 0.f, 0.f};
    const bf16_t* vp = qkv + base * D3_ + 2048 + h * 64 + lane;
    for (int k4 = 0; k4 < 144; k4++) {
        float4 pv[4];
        #pragma unroll
        for (int qi = 0; qi < 4; qi++)
            pv[qi] = *(const float4*)&p_lds[wid][qi][k4 * 4];
        #pragma unroll
        for (int kk = 0; kk < 4; kk++) {
            const float v = (float)vp[(long)(k4 * 4 + kk) * D3_];
            o[0] += ((const float*)&pv[0])[kk] * v;
            o[1] += ((const float*)&pv[1])[kk] * v;
            o[2] += ((const float*)&pv[2])[kk] * v;
            o[3] += ((const float*)&pv[3])[kk] * v;
        }
    }
    #pragma unroll
    for (int qi = 0; qi < 4; qi++)
        out[(base + r0 + qi) * (long)D_ + h * 64 + lane] = (bf16_t)o[qi];
}

// ---------------------------------------------------------------------------
// Temporal attention: groups (b,hw,h), T=16 tokens, causal. One wave per
// query time-step; lane k holds key k (k<16), lane d owns output dim d.
// ---------------------------------------------------------------------------
__global__ __launch_bounds__(256) void attn_temporal(const bf16_t* __restrict__ qkv,
                                                     bf16_t* __restrict__ out)
{
    __shared__ float q_lds[4][64];
    const int tid = threadIdx.x, lane = tid & 63, wid = tid >> 6;
    const int gid   = blockIdx.x;
    const int group = gid >> 2;             // (b*HW + hw) * NH + h
    const int chunk = gid & 3;
    const int h   = group % NH_;
    const int bhw = group / NH_;
    const int b   = bhw / HW_;
    const int hw  = bhw % HW_;
    const int tq  = chunk * 4 + wid;        // 0..15
    const long tok0   = (long)b * T_ * HW_ + hw;
    const long stride = (long)HW_ * D3_;

    q_lds[wid][lane] = 0.125f * (float)qkv[(tok0 + (long)tq * HW_) * D3_ + h * 64 + lane];
    __syncthreads();

    float s = -INFINITY;
    if (lane <= tq) {
        const bf16_t* kp = qkv + tok0 * D3_ + (long)lane * stride + 1024 + h * 64;
        float a2 = 0.f;
        #pragma unroll
        for (int d0 = 0; d0 < 8; d0++) {
            bf16x8 kv = *(const bf16x8*)(kp + d0 * 8);
            #pragma unroll
            for (int dd = 0; dd < 8; dd++)
                a2 += q_lds[wid][d0 * 8 + dd] * (float)kv[dd];
        }
        s = a2;
    }
    float m = s;
    #pragma unroll
    for (int off = 32; off; off >>= 1) m = fmaxf(m, __shfl_xor(m, off));
    float p = (lane <= tq) ? __expf(s - m) : 0.f;
    float lsum = p;
    #pragma unroll
    for (int off = 32; off; off >>= 1) lsum += __shfl_xor(lsum, off);
    const float pn = p / lsum;

    float o = 0.f;
    const bf16_t* vp = qkv + tok0 * D3_ + 2048 + h * 64 + lane;
    for (int k = 0; k <= tq; k++)
        o += __shfl(pn, k) * (float)vp[(long)k * stride];
    out[(tok0 + (long)tq * HW_) * (long)D_ + h * 64 + lane] = (bf16_t)o;
}

// ---------------------------------------------------------------------------
extern "C" void kernel_launch(void* const* d_in, const int* in_sizes, int n_in,
                              void* d_out, int out_size, void* d_ws, size_t ws_size,
                              hipStream_t stream)
{
    const float* x       = (const float*)d_in[0];
    const float* ws_qkv  = (const float*)d_in[1];
    const float* bs_qkv  = (const float*)d_in[2];
    const float* ws_proj = (const float*)d_in[3];
    const float* bs_proj = (const float*)d_in[4];
    const float* wt_qkv  = (const float*)d_in[5];
    const float* bt_qkv  = (const float*)d_in[6];
    const float* wt_proj = (const float*)d_in[7];
    const float* bt_proj = (const float*)d_in[8];
    float* out = (float*)d_out;
    (void)in_sizes; (void)n_in; (void)out_size;

    // workspace layout (bytes)
    char* ws = (char*)d_ws;
    bf16_t* qkv   = (bf16_t*)(ws);                  // 18432*3072*2 = 113,246,208
    bf16_t* x_bf  = (bf16_t*)(ws + 113246208L);     // 18432*1024*2 =  37,748,736
    bf16_t* att   = x_bf;                           // alias: att written after x_bf dead
    bf16_t* x1_bf = (bf16_t*)(ws + 150994944L);     //                 37,748,736
    bf16_t* wTqs  = (bf16_t*)(ws + 188743680L);     // 3072*1024*2 =    6,291,456
    bf16_t* wTps  = (bf16_t*)(ws + 195035136L);     // 1024*1024*2 =    2,097,152
    bf16_t* wTqt  = (bf16_t*)(ws + 197132288L);     //                  6,291,456
    bf16_t* wTpt  = (bf16_t*)(ws + 203423744L);     //                  2,097,152
    if (ws_size < 205520896UL) return;              // visible failure: out stays 0

    f2b<<<4096, 256, 0, stream>>>(x, x_bf, (long)TOK_ * D_);
    const dim3 tb(32, 8);
    transpose_k<<<dim3(96, 32), tb, 0, stream>>>(ws_qkv,  wTqs, 1024, 3072);
    transpose_k<<<dim3(32, 32), tb, 0, stream>>>(ws_proj, wTps, 1024, 1024);
    transpose_k<<<dim3(96, 32), tb, 0, stream>>>(wt_qkv,  wTqt, 1024, 3072);
    transpose_k<<<dim3(32, 32), tb, 0, stream>>>(wt_proj, wTpt, 1024, 1024);

    // ---- spatial branch ----  (x1 fp32 lives in d_out)
    gemm_bt<<<dim3(24, 144), 256, 0, stream>>>(x_bf, wTqs, bs_qkv, nullptr,
                                               qkv, nullptr, TOK_, D3_, D_);
    attn_spatial<<<18432, 256, 0, stream>>>(qkv, att);
    gemm_bt<<<dim3(8, 144), 256, 0, stream>>>(att, wTps, bs_proj, x,
                                              x1_bf, out, TOK_, D_, D_);
    // ---- temporal branch ----
    gemm_bt<<<dim3(24, 144), 256, 0, stream>>>(x1_bf, wTqt, bt_qkv, nullptr,
                                               qkv, nullptr, TOK_, D3_, D_);
    attn_temporal<<<73728, 256, 0, stream>>>(qkv, att);
    gemm_bt<<<dim3(8, 144), 256, 0, stream>>>(att, wTpt, bt_proj, out,
                                              nullptr, out, TOK_, D_, D_);
}

// Round 3
// 1091.082 us; speedup vs baseline: 3.7097x; 3.7097x over previous
//
#include <hip/hip_runtime.h>
#include <math.h>

typedef __bf16 bf16_t;
typedef __bf16 bf16x4 __attribute__((ext_vector_type(4)));
typedef __bf16 bf16x8 __attribute__((ext_vector_type(8)));
typedef float f32x4 __attribute__((ext_vector_type(4)));

#define GLDS(gp, lp) __builtin_amdgcn_global_load_lds( \
    (const __attribute__((address_space(1))) void*)(gp), \
    (__attribute__((address_space(3))) void*)(lp), 16, 0, 0)

static constexpr int B_    = 2;
static constexpr int T_    = 16;
static constexpr int HW_   = 576;
static constexpr int NH_   = 16;
static constexpr int TOK_  = B_ * T_ * HW_;   // 18432
static constexpr int D_    = 1024;
static constexpr int D3_   = 3072;

// ---------------------------------------------------------------------------
// fp32 -> bf16 elementwise convert (vectorized)
// ---------------------------------------------------------------------------
__global__ __launch_bounds__(256) void f2b(const float* __restrict__ in,
                                           bf16_t* __restrict__ out, long n)
{
    for (long i = ((long)blockIdx.x * 256 + threadIdx.x) * 4; i < n;
         i += (long)gridDim.x * 1024) {
        float4 v = *(const float4*)(in + i);
        bf16x4 o;
        o[0] = (bf16_t)v.x; o[1] = (bf16_t)v.y;
        o[2] = (bf16_t)v.z; o[3] = (bf16_t)v.w;
        *(bf16x4*)(out + i) = o;
    }
}

// ---------------------------------------------------------------------------
// Weight transpose + convert: out[N][K](bf16) = in[K][N](fp32), R=K, C=N
// ---------------------------------------------------------------------------
__global__ __launch_bounds__(256) void transpose_k(const float* __restrict__ in,
                                                   bf16_t* __restrict__ out,
                                                   int R, int C)
{
    __shared__ bf16_t tile[32][33];
    const int cb = blockIdx.x * 32, rb = blockIdx.y * 32;
    const int tx = threadIdx.x, ty = threadIdx.y;  // 32 x 8
    #pragma unroll
    for (int i = 0; i < 32; i += 8)
        tile[ty + i][tx] = (bf16_t)in[(long)(rb + ty + i) * C + cb + tx];
    __syncthreads();
    #pragma unroll
    for (int i = 0; i < 32; i += 8)
        out[(long)(cb + ty + i) * R + rb + tx] = tile[tx][ty + i];
}

// ---------------------------------------------------------------------------
// V transpose: vt[g=(bt*16+h)][d=64][hw=576] = qkv[bt*576+hw][2048+h*64+d]
// ---------------------------------------------------------------------------
__global__ __launch_bounds__(256) void vtrans(const bf16_t* __restrict__ qkv,
                                              bf16_t* __restrict__ vt)
{
    __shared__ bf16_t t[64][68];
    const int tid = threadIdx.x;
    const int hw0 = blockIdx.x * 64;          // 9 chunks
    const int g   = blockIdx.y;               // 512 groups
    const int bt  = g >> 4, h = g & 15;

    // load 64 hw-rows x 64 d, vectorized 16B
    #pragma unroll
    for (int i = 0; i < 2; i++) {
        const int c = i * 256 + tid;          // 0..511
        const int row = c >> 3, di = (c & 7) * 8;
        *(bf16x8*)&t[row][di] =
            *(const bf16x8*)(qkv + ((long)bt * HW_ + hw0 + row) * D3_ + 2048 + h * 64 + di);
    }
    __syncthreads();
    // store transposed, vectorized 16B along hw
    #pragma unroll
    for (int i = 0; i < 2; i++) {
        const int c = i * 256 + tid;
        const int dd = c >> 3, hwl = (c & 7) * 8;
        bf16x8 v;
        #pragma unroll
        for (int jj = 0; jj < 8; jj++) v[jj] = t[hwl + jj][dd];
        *(bf16x8*)(vt + (long)g * (64 * 576) + (long)dd * 576 + hw0 + hwl) = v;
    }
}

// ---------------------------------------------------------------------------
// GEMM: C = A[M][K](bf16) * BT[N][K](bf16)^T + bias[N](f32) (+ res[M][N](f32))
// outputs: Cb (bf16, optional) and/or Cf (f32, optional). fp32 accum.
// 128x128 tile, BK=32, 4 waves, 16x16x32 MFMA (m97 structure).
// ---------------------------------------------------------------------------
__global__ __launch_bounds__(256) void gemm_bt(const bf16_t* __restrict__ A,
                                               const bf16_t* __restrict__ BT,
                                               const float* __restrict__ bias,
                                               const float* __restrict__ res,
                                               bf16_t* __restrict__ Cb,
                                               float* __restrict__ Cf,
                                               int M, int N, int K)
{
    __shared__ bf16_t As[128 * 32];
    __shared__ bf16_t Bs[128 * 32];
    const int tid  = threadIdx.x;
    const int lane = tid & 63, wid = tid >> 6;
    const int wr   = wid >> 1, wc = wid & 1;
    const long row0 = (long)blockIdx.y * 128;
    const long col0 = (long)blockIdx.x * 128;
    const int  sr   = tid >> 2;        // 0..63
    const int  sc   = (tid & 3) * 8;   // 0,8,16,24
    const bf16_t* Ag = A  + (row0 + sr) * (long)K + sc;
    const bf16_t* Bg = BT + (col0 + sr) * (long)K + sc;

    f32x4 acc[4][4] = {};

    for (int k0 = 0; k0 < K; k0 += 32) {
        GLDS(Ag + k0,                &As[tid * 8]);
        GLDS(Ag + 64 * (long)K + k0, &As[2048 + tid * 8]);
        GLDS(Bg + k0,                &Bs[tid * 8]);
        GLDS(Bg + 64 * (long)K + k0, &Bs[2048 + tid * 8]);
        __syncthreads();

        bf16x8 a[4], b[4];
        #pragma unroll
        for (int i = 0; i < 4; i++)
            a[i] = *(const bf16x8*)&As[(wr * 64 + i * 16 + (lane & 15)) * 32 + (lane >> 4) * 8];
        #pragma unroll
        for (int j = 0; j < 4; j++)
            b[j] = *(const bf16x8*)&Bs[(wc * 64 + j * 16 + (lane & 15)) * 32 + (lane >> 4) * 8];
        #pragma unroll
        for (int i = 0; i < 4; i++)
            #pragma unroll
            for (int j = 0; j < 4; j++)
                acc[i][j] = __builtin_amdgcn_mfma_f32_16x16x32_bf16(a[i], b[j], acc[i][j], 0, 0, 0);
        __syncthreads();
    }

    // epilogue: C/D frag mapping col=lane&15, row=(lane>>4)*4+reg  [m89]
    #pragma unroll
    for (int i = 0; i < 4; i++) {
        #pragma unroll
        for (int j = 0; j < 4; j++) {
            #pragma unroll
            for (int r = 0; r < 4; r++) {
                const long row = row0 + wr * 64 + i * 16 + ((lane >> 4) * 4 + r);
                const long col = col0 + wc * 64 + j * 16 + (lane & 15);
                float v = acc[i][j][r] + bias[col];
                if (res) v += res[row * (long)N + col];
                if (Cf)  Cf[row * (long)N + col] = v;
                if (Cb)  Cb[row * (long)N + col] = (bf16_t)v;
            }
        }
    }
}

// ---------------------------------------------------------------------------
// Spatial attention, MFMA flash-style. Block = (qt, g=(bt,h)), 4 waves,
// each wave owns 16 Q-rows. K-tiles of 64 keys staged in LDS (pre-swizzled
// source -> linear LDS -> swizzled read, bank-conflict-free ds_read_b128).
// ---------------------------------------------------------------------------
__global__ __launch_bounds__(256) void attn_spatial(const bf16_t* __restrict__ qkv,
                                                    const bf16_t* __restrict__ vt,
                                                    bf16_t* __restrict__ out)
{
    __shared__ bf16_t Ks[64 * 64];
    __shared__ bf16_t Vts[64 * 64];
    __shared__ bf16_t Pws[4][16 * 72];    // per-wave P tile, stride 72 (pad)
    const int tid = threadIdx.x, lane = tid & 63, w = tid >> 6;
    const int qt = blockIdx.x;            // 0..8
    const int g  = blockIdx.y;            // 0..511
    const int h  = g & 15, bt = g >> 4;
    const long base = (long)bt * HW_;
    const int l15 = lane & 15, lhi = lane >> 4;
    const int qrow0 = qt * 64 + w * 16;

    // Q fragments (A-operand): lane holds Q[qrow0 + l15][kk*32 + lhi*8 ..+7]
    bf16x8 q[2];
    #pragma unroll
    for (int kk = 0; kk < 2; kk++)
        q[kk] = *(const bf16x8*)(qkv + (base + qrow0 + l15) * D3_ + h * 64 + kk * 32 + lhi * 8);

    const bf16_t* Kg = qkv + base * D3_ + 1024 + h * 64;
    const bf16_t* Vg = vt + (long)g * (64 * 576);

    float m[4], l[4];
    f32x4 o[4];
    #pragma unroll
    for (int r = 0; r < 4; r++) { m[r] = -INFINITY; l[r] = 0.f; }
    #pragma unroll
    for (int j = 0; j < 4; j++) o[j] = (f32x4){0.f, 0.f, 0.f, 0.f};

    for (int kt = 0; kt < 9; kt++) {
        __syncthreads();   // prev tile's LDS reads done
        // stage K tile + V^T tile (linear LDS dest, swizzled global source)
        #pragma unroll
        for (int i = 0; i < 2; i++) {
            const int c = i * 256 + tid;          // 16B chunk id, 0..511
            const int r = c >> 3, cb = (c & 7) << 4;
            const int csrc = cb ^ ((r & 7) << 4);
            GLDS(Kg + (long)(kt * 64 + r) * D3_ + (csrc >> 1), (char*)Ks + c * 16);
            GLDS(Vg + (long)r * 576 + kt * 64 + (csrc >> 1), (char*)Vts + c * 16);
        }
        __syncthreads();   // drains vmcnt before use

        // S = Q K^T  (per wave: 16 rows x 64 keys)
        f32x4 acc[4] = {};
        #pragma unroll
        for (int j = 0; j < 4; j++) {
            const int key = j * 16 + l15;
            #pragma unroll
            for (int kk = 0; kk < 2; kk++) {
                const int boff = key * 128 + ((kk * 64 + lhi * 16) ^ ((key & 7) << 4));
                bf16x8 kb = *(const bf16x8*)((const char*)Ks + boff);
                acc[j] = __builtin_amdgcn_mfma_f32_16x16x32_bf16(q[kk], kb, acc[j], 0, 0, 0);
            }
        }

        // online softmax per row (row = qrow0 + lhi*4 + r; 16-lane row group)
        #pragma unroll
        for (int j = 0; j < 4; j++) acc[j] = acc[j] * 0.125f;
        #pragma unroll
        for (int r = 0; r < 4; r++) {
            float rm = fmaxf(fmaxf(acc[0][r], acc[1][r]), fmaxf(acc[2][r], acc[3][r]));
            #pragma unroll
            for (int off = 1; off < 16; off <<= 1) rm = fmaxf(rm, __shfl_xor(rm, off));
            const float mn = fmaxf(m[r], rm);
            const float sc = __expf(m[r] - mn);
            m[r] = mn;
            float rs = 0.f;
            #pragma unroll
            for (int j = 0; j < 4; j++) {
                const float p = __expf(acc[j][r] - mn);
                acc[j][r] = p;
                rs += p;
            }
            #pragma unroll
            for (int off = 1; off < 16; off <<= 1) rs += __shfl_xor(rs, off);
            l[r] = l[r] * sc + rs;
            #pragma unroll
            for (int j = 0; j < 4; j++) o[j][r] *= sc;
            // write P tile (bf16) for PV A-fragments
            #pragma unroll
            for (int j = 0; j < 4; j++)
                Pws[w][(lhi * 4 + r) * 72 + j * 16 + l15] = (bf16_t)acc[j][r];
        }
        __syncthreads();   // orders P write -> P read (and is the 3rd barrier)

        // O += P V   (A = P [16 x 64keys], B = V^T tile [d][key])
        bf16x8 pa[2];
        #pragma unroll
        for (int kk = 0; kk < 2; kk++)
            pa[kk] = *(const bf16x8*)&Pws[w][l15 * 72 + kk * 32 + lhi * 8];
        #pragma unroll
        for (int j = 0; j < 4; j++) {
            const int vrow = j * 16 + l15;   // d index
            #pragma unroll
            for (int kk = 0; kk < 2; kk++) {
                const int boff = vrow * 128 + ((kk * 64 + lhi * 16) ^ ((vrow & 7) << 4));
                bf16x8 vb = *(const bf16x8*)((const char*)Vts + boff);
                o[j] = __builtin_amdgcn_mfma_f32_16x16x32_bf16(pa[kk], vb, o[j], 0, 0, 0);
            }
        }
    }

    // epilogue: normalize and store
    #pragma unroll
    for (int r = 0; r < 4; r++) {
        const float inv = 1.f / l[r];
        const long row = base + qrow0 + lhi * 4 + r;
        #pragma unroll
        for (int j = 0; j < 4; j++)
            out[row * (long)D_ + h * 64 + j * 16 + l15] = (bf16_t)(o[j][r] * inv);
    }
}

// ---------------------------------------------------------------------------
// Temporal attention: groups (b,hw,h), T=16 tokens, causal. One wave per
// query time-step; lane k holds key k (k<16), lane d owns output dim d.
// ---------------------------------------------------------------------------
__global__ __launch_bounds__(256) void attn_temporal(const bf16_t* __restrict__ qkv,
                                                     bf16_t* __restrict__ out)
{
    __shared__ float q_lds[4][64];
    const int tid = threadIdx.x, lane = tid & 63, wid = tid >> 6;
    const int gid   = blockIdx.x;
    const int group = gid >> 2;             // (b*HW + hw) * NH + h
    const int chunk = gid & 3;
    const int h   = group % NH_;
    const int bhw = group / NH_;
    const int b   = bhw / HW_;
    const int hw  = bhw % HW_;
    const int tq  = chunk * 4 + wid;        // 0..15
    const long tok0   = (long)b * T_ * HW_ + hw;
    const long stride = (long)HW_ * D3_;

    q_lds[wid][lane] = 0.125f * (float)qkv[(tok0 + (long)tq * HW_) * D3_ + h * 64 + lane];
    __syncthreads();

    float s = -INFINITY;
    if (lane <= tq) {
        const bf16_t* kp = qkv + tok0 * D3_ + (long)lane * stride + 1024 + h * 64;
        float a2 = 0.f;
        #pragma unroll
        for (int d0 = 0; d0 < 8; d0++) {
            bf16x8 kv = *(const bf16x8*)(kp + d0 * 8);
            #pragma unroll
            for (int dd = 0; dd < 8; dd++)
                a2 += q_lds[wid][d0 * 8 + dd] * (float)kv[dd];
        }
        s = a2;
    }
    float m = s;
    #pragma unroll
    for (int off = 32; off; off >>= 1) m = fmaxf(m, __shfl_xor(m, off));
    float p = (lane <= tq) ? __expf(s - m) : 0.f;
    float lsum = p;
    #pragma unroll
    for (int off = 32; off; off >>= 1) lsum += __shfl_xor(lsum, off);
    const float pn = p / lsum;

    float o = 0.f;
    const bf16_t* vp = qkv + tok0 * D3_ + 2048 + h * 64 + lane;
    for (int k = 0; k <= tq; k++)
        o += __shfl(pn, k) * (float)vp[(long)k * stride];
    out[(tok0 + (long)tq * HW_) * (long)D_ + h * 64 + lane] = (bf16_t)o;
}

// ---------------------------------------------------------------------------
extern "C" void kernel_launch(void* const* d_in, const int* in_sizes, int n_in,
                              void* d_out, int out_size, void* d_ws, size_t ws_size,
                              hipStream_t stream)
{
    const float* x       = (const float*)d_in[0];
    const float* ws_qkv  = (const float*)d_in[1];
    const float* bs_qkv  = (const float*)d_in[2];
    const float* ws_proj = (const float*)d_in[3];
    const float* bs_proj = (const float*)d_in[4];
    const float* wt_qkv  = (const float*)d_in[5];
    const float* bt_qkv  = (const float*)d_in[6];
    const float* wt_proj = (const float*)d_in[7];
    const float* bt_proj = (const float*)d_in[8];
    float* out = (float*)d_out;
    (void)in_sizes; (void)n_in; (void)out_size;

    // workspace layout (bytes)
    char* ws = (char*)d_ws;
    bf16_t* qkv   = (bf16_t*)(ws);                  // 18432*3072*2 = 113,246,208
    bf16_t* x_bf  = (bf16_t*)(ws + 113246208L);     // 18432*1024*2 =  37,748,736
    bf16_t* att   = x_bf;                           // alias: att written after x_bf dead
    bf16_t* x1_bf = (bf16_t*)(ws + 150994944L);     //                 37,748,736
    bf16_t* vt    = x1_bf;                          // alias: vt dead before x1_bf written
    bf16_t* wTqs  = (bf16_t*)(ws + 188743680L);     // 3072*1024*2 =    6,291,456
    bf16_t* wTps  = (bf16_t*)(ws + 195035136L);     // 1024*1024*2 =    2,097,152
    bf16_t* wTqt  = (bf16_t*)(ws + 197132288L);     //                  6,291,456
    bf16_t* wTpt  = (bf16_t*)(ws + 203423744L);     //                  2,097,152
    if (ws_size < 205520896UL) return;              // visible failure: out stays 0

    f2b<<<4096, 256, 0, stream>>>(x, x_bf, (long)TOK_ * D_);
    const dim3 tb(32, 8);
    transpose_k<<<dim3(96, 32), tb, 0, stream>>>(ws_qkv,  wTqs, 1024, 3072);
    transpose_k<<<dim3(32, 32), tb, 0, stream>>>(ws_proj, wTps, 1024, 1024);
    transpose_k<<<dim3(96, 32), tb, 0, stream>>>(wt_qkv,  wTqt, 1024, 3072);
    transpose_k<<<dim3(32, 32), tb, 0, stream>>>(wt_proj, wTpt, 1024, 1024);

    // ---- spatial branch ----  (x1 fp32 lives in d_out)
    gemm_bt<<<dim3(24, 144), 256, 0, stream>>>(x_bf, wTqs, bs_qkv, nullptr,
                                               qkv, nullptr, TOK_, D3_, D_);
    vtrans<<<dim3(9, 512), 256, 0, stream>>>(qkv, vt);
    attn_spatial<<<dim3(9, 512), 256, 0, stream>>>(qkv, vt, att);
    gemm_bt<<<dim3(8, 144), 256, 0, stream>>>(att, wTps, bs_proj, x,
                                              x1_bf, out, TOK_, D_, D_);
    // ---- temporal branch ----
    gemm_bt<<<dim3(24, 144), 256, 0, stream>>>(x1_bf, wTqt, bt_qkv, nullptr,
                                               qkv, nullptr, TOK_, D3_, D_);
    attn_temporal<<<73728, 256, 0, stream>>>(qkv, att);
    gemm_bt<<<dim3(8, 144), 256, 0, stream>>>(att, wTpt, bt_proj, out,
                                              nullptr, out, TOK_, D_, D_);
}

// Round 4
// 1024.290 us; speedup vs baseline: 3.9516x; 1.0652x over previous
//
#include <hip/hip_runtime.h>
#include <math.h>

typedef __bf16 bf16_t;
typedef __bf16 bf16x4 __attribute__((ext_vector_type(4)));
typedef __bf16 bf16x8 __attribute__((ext_vector_type(8)));
typedef float f32x4 __attribute__((ext_vector_type(4)));

#define GLDS(gp, lp) __builtin_amdgcn_global_load_lds( \
    (const __attribute__((address_space(1))) void*)(gp), \
    (__attribute__((address_space(3))) void*)(lp), 16, 0, 0)

static constexpr int B_    = 2;
static constexpr int T_    = 16;
static constexpr int HW_   = 576;
static constexpr int NH_   = 16;
static constexpr int TOK_  = B_ * T_ * HW_;   // 18432
static constexpr int D_    = 1024;
static constexpr int D3_   = 3072;

// ---------------------------------------------------------------------------
// fp32 -> bf16 elementwise convert (vectorized)
// ---------------------------------------------------------------------------
__global__ __launch_bounds__(256) void f2b(const float* __restrict__ in,
                                           bf16_t* __restrict__ out, long n)
{
    for (long i = ((long)blockIdx.x * 256 + threadIdx.x) * 4; i < n;
         i += (long)gridDim.x * 1024) {
        float4 v = *(const float4*)(in + i);
        bf16x4 o;
        o[0] = (bf16_t)v.x; o[1] = (bf16_t)v.y;
        o[2] = (bf16_t)v.z; o[3] = (bf16_t)v.w;
        *(bf16x4*)(out + i) = o;
    }
}

// ---------------------------------------------------------------------------
// Weight transpose + convert: out[N][K](bf16) = in[K][N](fp32), R=K, C=N
// ---------------------------------------------------------------------------
__global__ __launch_bounds__(256) void transpose_k(const float* __restrict__ in,
                                                   bf16_t* __restrict__ out,
                                                   int R, int C)
{
    __shared__ bf16_t tile[32][33];
    const int cb = blockIdx.x * 32, rb = blockIdx.y * 32;
    const int tx = threadIdx.x, ty = threadIdx.y;  // 32 x 8
    #pragma unroll
    for (int i = 0; i < 32; i += 8)
        tile[ty + i][tx] = (bf16_t)in[(long)(rb + ty + i) * C + cb + tx];
    __syncthreads();
    #pragma unroll
    for (int i = 0; i < 32; i += 8)
        out[(long)(cb + ty + i) * R + rb + tx] = tile[tx][ty + i];
}

// ---------------------------------------------------------------------------
// V transpose (spatial): vt[g=(bt*16+h)][d=64][hw=576]
// ---------------------------------------------------------------------------
__global__ __launch_bounds__(256) void vtrans(const bf16_t* __restrict__ qkv,
                                              bf16_t* __restrict__ vt)
{
    __shared__ bf16_t t[64][68];
    const int tid = threadIdx.x;
    const int hw0 = blockIdx.x * 64;          // 9 chunks
    const int g   = blockIdx.y;               // 512 groups
    const int bt  = g >> 4, h = g & 15;

    #pragma unroll
    for (int i = 0; i < 2; i++) {
        const int c = i * 256 + tid;          // 0..511
        const int row = c >> 3, di = (c & 7) * 8;
        *(bf16x8*)&t[row][di] =
            *(const bf16x8*)(qkv + ((long)bt * HW_ + hw0 + row) * D3_ + 2048 + h * 64 + di);
    }
    __syncthreads();
    #pragma unroll
    for (int i = 0; i < 2; i++) {
        const int c = i * 256 + tid;
        const int dd = c >> 3, hwl = (c & 7) * 8;
        bf16x8 v;
        #pragma unroll
        for (int jj = 0; jj < 8; jj++) v[jj] = t[hwl + jj][dd];
        *(bf16x8*)(vt + (long)g * (64 * 576) + (long)dd * 576 + hw0 + hwl) = v;
    }
}

// ---------------------------------------------------------------------------
// V transpose (temporal, from permuted qkv_t): vtt[g'=(bhw*16+h)][d=64][t=16]
// ---------------------------------------------------------------------------
__global__ __launch_bounds__(256) void vtrans_t(const bf16_t* __restrict__ qkv_t,
                                                bf16_t* __restrict__ vtt)
{
    __shared__ bf16_t tile[16][1026];
    const int tid = threadIdx.x;
    const long bhw = blockIdx.x;              // 0..1151
    #pragma unroll
    for (int it = 0; it < 8; it++) {
        const int c = it * 256 + tid;         // 0..2047 vec8 chunks
        const int row = c >> 7, col = (c & 127) * 8;
        *(bf16x8*)&tile[row][col] =
            *(const bf16x8*)(qkv_t + (bhw * 16 + row) * D3_ + 2048 + col);
    }
    __syncthreads();
    #pragma unroll
    for (int it = 0; it < 4; it++) {
        const int hd = it * 256 + tid;        // h*64+d, 0..1023
        bf16x8 v0, v1;
        #pragma unroll
        for (int t = 0; t < 8; t++) v0[t] = tile[t][hd];
        #pragma unroll
        for (int t = 0; t < 8; t++) v1[t] = tile[8 + t][hd];
        bf16_t* dst = vtt + (bhw * 16 + (hd >> 6)) * 1024 + (long)(hd & 63) * 16;
        *(bf16x8*)dst = v0;
        *(bf16x8*)(dst + 8) = v1;
    }
}

// ---------------------------------------------------------------------------
// GEMM: C = A[M][K](bf16) * BT[N][K](bf16)^T + bias[N](f32) (+ res[M][N](f32))
// outputs: Cb (bf16, optional) and/or Cf (f32, optional). fp32 accum.
// tperm: store rows permuted (b,t,hw)->(b,hw,t) for the temporal branch.
// ---------------------------------------------------------------------------
__global__ __launch_bounds__(256) void gemm_bt(const bf16_t* __restrict__ A,
                                               const bf16_t* __restrict__ BT,
                                               const float* __restrict__ bias,
                                               const float* __restrict__ res,
                                               bf16_t* __restrict__ Cb,
                                               float* __restrict__ Cf,
                                               int M, int N, int K, int tperm)
{
    __shared__ bf16_t As[128 * 32];
    __shared__ bf16_t Bs[128 * 32];
    const int tid  = threadIdx.x;
    const int lane = tid & 63, wid = tid >> 6;
    const int wr   = wid >> 1, wc = wid & 1;
    const long row0 = (long)blockIdx.y * 128;
    const long col0 = (long)blockIdx.x * 128;
    const int  sr   = tid >> 2;        // 0..63
    const int  sc   = (tid & 3) * 8;   // 0,8,16,24
    const bf16_t* Ag = A  + (row0 + sr) * (long)K + sc;
    const bf16_t* Bg = BT + (col0 + sr) * (long)K + sc;

    f32x4 acc[4][4] = {};

    for (int k0 = 0; k0 < K; k0 += 32) {
        GLDS(Ag + k0,                &As[tid * 8]);
        GLDS(Ag + 64 * (long)K + k0, &As[2048 + tid * 8]);
        GLDS(Bg + k0,                &Bs[tid * 8]);
        GLDS(Bg + 64 * (long)K + k0, &Bs[2048 + tid * 8]);
        __syncthreads();

        bf16x8 a[4], b[4];
        #pragma unroll
        for (int i = 0; i < 4; i++)
            a[i] = *(const bf16x8*)&As[(wr * 64 + i * 16 + (lane & 15)) * 32 + (lane >> 4) * 8];
        #pragma unroll
        for (int j = 0; j < 4; j++)
            b[j] = *(const bf16x8*)&Bs[(wc * 64 + j * 16 + (lane & 15)) * 32 + (lane >> 4) * 8];
        #pragma unroll
        for (int i = 0; i < 4; i++)
            #pragma unroll
            for (int j = 0; j < 4; j++)
                acc[i][j] = __builtin_amdgcn_mfma_f32_16x16x32_bf16(a[i], b[j], acc[i][j], 0, 0, 0);
        __syncthreads();
    }

    // epilogue: C/D frag mapping col=lane&15, row=(lane>>4)*4+reg  [m89]
    #pragma unroll
    for (int i = 0; i < 4; i++) {
        #pragma unroll
        for (int j = 0; j < 4; j++) {
            #pragma unroll
            for (int r = 0; r < 4; r++) {
                const long row = row0 + wr * 64 + i * 16 + ((lane >> 4) * 4 + r);
                const long col = col0 + wc * 64 + j * 16 + (lane & 15);
                long srow = row;
                if (tperm) {
                    const int ri  = (int)row;
                    const int bb  = ri / (T_ * HW_);
                    const int rem = ri - bb * (T_ * HW_);
                    const int tt  = rem / HW_;
                    const int hh  = rem - tt * HW_;
                    srow = ((long)bb * HW_ + hh) * T_ + tt;
                }
                float v = acc[i][j][r] + bias[col];
                if (res) v += res[row * (long)N + col];
                if (Cf)  Cf[srow * (long)N + col] = v;
                if (Cb)  Cb[srow * (long)N + col] = (bf16_t)v;
            }
        }
    }
}

// ---------------------------------------------------------------------------
// Spatial attention, MFMA flash-style (unchanged from R3).
// ---------------------------------------------------------------------------
__global__ __launch_bounds__(256) void attn_spatial(const bf16_t* __restrict__ qkv,
                                                    const bf16_t* __restrict__ vt,
                                                    bf16_t* __restrict__ out)
{
    __shared__ bf16_t Ks[64 * 64];
    __shared__ bf16_t Vts[64 * 64];
    __shared__ bf16_t Pws[4][16 * 72];
    const int tid = threadIdx.x, lane = tid & 63, w = tid >> 6;
    const int qt = blockIdx.x;            // 0..8
    const int g  = blockIdx.y;            // 0..511
    const int h  = g & 15, bt = g >> 4;
    const long base = (long)bt * HW_;
    const int l15 = lane & 15, lhi = lane >> 4;
    const int qrow0 = qt * 64 + w * 16;

    bf16x8 q[2];
    #pragma unroll
    for (int kk = 0; kk < 2; kk++)
        q[kk] = *(const bf16x8*)(qkv + (base + qrow0 + l15) * D3_ + h * 64 + kk * 32 + lhi * 8);

    const bf16_t* Kg = qkv + base * D3_ + 1024 + h * 64;
    const bf16_t* Vg = vt + (long)g * (64 * 576);

    float m[4], l[4];
    f32x4 o[4];
    #pragma unroll
    for (int r = 0; r < 4; r++) { m[r] = -INFINITY; l[r] = 0.f; }
    #pragma unroll
    for (int j = 0; j < 4; j++) o[j] = (f32x4){0.f, 0.f, 0.f, 0.f};

    for (int kt = 0; kt < 9; kt++) {
        __syncthreads();
        #pragma unroll
        for (int i = 0; i < 2; i++) {
            const int c = i * 256 + tid;
            const int r = c >> 3, cb = (c & 7) << 4;
            const int csrc = cb ^ ((r & 7) << 4);
            GLDS(Kg + (long)(kt * 64 + r) * D3_ + (csrc >> 1), (char*)Ks + c * 16);
            GLDS(Vg + (long)r * 576 + kt * 64 + (csrc >> 1), (char*)Vts + c * 16);
        }
        __syncthreads();

        f32x4 acc[4] = {};
        #pragma unroll
        for (int j = 0; j < 4; j++) {
            const int key = j * 16 + l15;
            #pragma unroll
            for (int kk = 0; kk < 2; kk++) {
                const int boff = key * 128 + ((kk * 64 + lhi * 16) ^ ((key & 7) << 4));
                bf16x8 kb = *(const bf16x8*)((const char*)Ks + boff);
                acc[j] = __builtin_amdgcn_mfma_f32_16x16x32_bf16(q[kk], kb, acc[j], 0, 0, 0);
            }
        }

        #pragma unroll
        for (int j = 0; j < 4; j++) acc[j] = acc[j] * 0.125f;
        #pragma unroll
        for (int r = 0; r < 4; r++) {
            float rm = fmaxf(fmaxf(acc[0][r], acc[1][r]), fmaxf(acc[2][r], acc[3][r]));
            #pragma unroll
            for (int off = 1; off < 16; off <<= 1) rm = fmaxf(rm, __shfl_xor(rm, off));
            const float mn = fmaxf(m[r], rm);
            const float sc = __expf(m[r] - mn);
            m[r] = mn;
            float rs = 0.f;
            #pragma unroll
            for (int j = 0; j < 4; j++) {
                const float p = __expf(acc[j][r] - mn);
                acc[j][r] = p;
                rs += p;
            }
            #pragma unroll
            for (int off = 1; off < 16; off <<= 1) rs += __shfl_xor(rs, off);
            l[r] = l[r] * sc + rs;
            #pragma unroll
            for (int j = 0; j < 4; j++) o[j][r] *= sc;
            #pragma unroll
            for (int j = 0; j < 4; j++)
                Pws[w][(lhi * 4 + r) * 72 + j * 16 + l15] = (bf16_t)acc[j][r];
        }
        __syncthreads();

        bf16x8 pa[2];
        #pragma unroll
        for (int kk = 0; kk < 2; kk++)
            pa[kk] = *(const bf16x8*)&Pws[w][l15 * 72 + kk * 32 + lhi * 8];
        #pragma unroll
        for (int j = 0; j < 4; j++) {
            const int vrow = j * 16 + l15;
            #pragma unroll
            for (int kk = 0; kk < 2; kk++) {
                const int boff = vrow * 128 + ((kk * 64 + lhi * 16) ^ ((vrow & 7) << 4));
                bf16x8 vb = *(const bf16x8*)((const char*)Vts + boff);
                o[j] = __builtin_amdgcn_mfma_f32_16x16x32_bf16(pa[kk], vb, o[j], 0, 0, 0);
            }
        }
    }

    #pragma unroll
    for (int r = 0; r < 4; r++) {
        const float inv = 1.f / l[r];
        const long row = base + qrow0 + lhi * 4 + r;
        #pragma unroll
        for (int j = 0; j < 4; j++)
            out[row * (long)D_ + h * 64 + j * 16 + l15] = (bf16_t)(o[j][r] * inv);
    }
}

// ---------------------------------------------------------------------------
// Temporal attention, MFMA. Block = (b,hw), 4 waves x 4 heads. Reads the
// permuted qkv_t (rows (b,hw,t)) and vtt[g'][d][t]; causal softmax fully
// in-register (16-lane row groups). PV: K=32 MFMA, keys 16..31 zero in A & B.
// ---------------------------------------------------------------------------
__global__ __launch_bounds__(256) void attn_temporal(const bf16_t* __restrict__ qkv_t,
                                                     const bf16_t* __restrict__ vtt,
                                                     bf16_t* __restrict__ out)
{
    __shared__ bf16_t Plds[4][16 * 24];
    const int tid = threadIdx.x, lane = tid & 63, w = tid >> 6;
    const int l15 = lane & 15, lhi = lane >> 4;
    const int bhw = blockIdx.x;            // 0..1151
    const int b = bhw / HW_, hw = bhw % HW_;
    const long base_row = (long)bhw * T_;
    const bf16_t* qrow = qkv_t + (base_row + l15) * D3_;

    #pragma unroll
    for (int i = 0; i < 4; i++) {
        const int h = w * 4 + i;
        // Q A-frag (row=t_q=l15, k=d), K B-frag (row=t_k=l15, k=d)
        bf16x8 q0 = *(const bf16x8*)(qrow + h * 64 + lhi * 8);
        bf16x8 q1 = *(const bf16x8*)(qrow + h * 64 + 32 + lhi * 8);
        bf16x8 k0 = *(const bf16x8*)(qrow + 1024 + h * 64 + lhi * 8);
        bf16x8 k1 = *(const bf16x8*)(qrow + 1024 + h * 64 + 32 + lhi * 8);
        f32x4 acc = {};
        acc = __builtin_amdgcn_mfma_f32_16x16x32_bf16(q0, k0, acc, 0, 0, 0);
        acc = __builtin_amdgcn_mfma_f32_16x16x32_bf16(q1, k1, acc, 0, 0, 0);

        // causal softmax; C-layout: col=t_k=l15, row=t_q=lhi*4+r
        #pragma unroll
        for (int r = 0; r < 4; r++) {
            const int tq = lhi * 4 + r;
            float s = (l15 <= tq) ? acc[r] * 0.125f : -INFINITY;
            float mv = s;
            #pragma unroll
            for (int off = 1; off < 16; off <<= 1) mv = fmaxf(mv, __shfl_xor(mv, off));
            float p = __expf(s - mv);
            float sum = p;
            #pragma unroll
            for (int off = 1; off < 16; off <<= 1) sum += __shfl_xor(sum, off);
            Plds[w][tq * 24 + l15] = (bf16_t)(p / sum);
        }
        __builtin_amdgcn_sched_barrier(0);   // pin P-write before P-read

        // P A-frag: row=t_q=l15, k=t_k (0..15 real, 16..31 zero)
        bf16x8 pa = {};
        if (lhi < 2) pa = *(const bf16x8*)&Plds[w][l15 * 24 + lhi * 8];

        const bf16_t* vg = vtt + ((long)bhw * 16 + h) * 1024;
        #pragma unroll
        for (int j = 0; j < 4; j++) {
            bf16x8 vb = {};
            if (lhi < 2) vb = *(const bf16x8*)(vg + (long)(j * 16 + l15) * 16 + lhi * 8);
            f32x4 o = {};
            o = __builtin_amdgcn_mfma_f32_16x16x32_bf16(pa, vb, o, 0, 0, 0);
            #pragma unroll
            for (int r = 0; r < 4; r++) {
                const int tq = lhi * 4 + r;
                out[(((long)b * T_ + tq) * HW_ + hw) * D_ + h * 64 + j * 16 + l15] = (bf16_t)o[r];
            }
        }
        __builtin_amdgcn_sched_barrier(0);   // don't let next head's reads cross
    }
}

// ---------------------------------------------------------------------------
extern "C" void kernel_launch(void* const* d_in, const int* in_sizes, int n_in,
                              void* d_out, int out_size, void* d_ws, size_t ws_size,
                              hipStream_t stream)
{
    const float* x       = (const float*)d_in[0];
    const float* ws_qkv  = (const float*)d_in[1];
    const float* bs_qkv  = (const float*)d_in[2];
    const float* ws_proj = (const float*)d_in[3];
    const float* bs_proj = (const float*)d_in[4];
    const float* wt_qkv  = (const float*)d_in[5];
    const float* bt_qkv  = (const float*)d_in[6];
    const float* wt_proj = (const float*)d_in[7];
    const float* bt_proj = (const float*)d_in[8];
    float* out = (float*)d_out;
    (void)in_sizes; (void)n_in; (void)out_size;

    // workspace layout (bytes)
    char* ws = (char*)d_ws;
    bf16_t* qkv   = (bf16_t*)(ws);                  // 18432*3072*2 = 113,246,208
    bf16_t* x_bf  = (bf16_t*)(ws + 113246208L);     // 18432*1024*2 =  37,748,736
    bf16_t* att   = x_bf;                           // alias: att written after x_bf dead
    bf16_t* x1_bf = (bf16_t*)(ws + 150994944L);     //                 37,748,736
    bf16_t* vt    = x1_bf;                          // alias: vt dead before x1_bf written
    bf16_t* vtt   = x1_bf;                          // alias: vtt written after x1_bf dead
    bf16_t* wTqs  = (bf16_t*)(ws + 188743680L);     // 3072*1024*2 =    6,291,456
    bf16_t* wTps  = (bf16_t*)(ws + 195035136L);     // 1024*1024*2 =    2,097,152
    bf16_t* wTqt  = (bf16_t*)(ws + 197132288L);     //                  6,291,456
    bf16_t* wTpt  = (bf16_t*)(ws + 203423744L);     //                  2,097,152
    if (ws_size < 205520896UL) return;              // visible failure: out stays 0

    f2b<<<4096, 256, 0, stream>>>(x, x_bf, (long)TOK_ * D_);
    const dim3 tb(32, 8);
    transpose_k<<<dim3(96, 32), tb, 0, stream>>>(ws_qkv,  wTqs, 1024, 3072);
    transpose_k<<<dim3(32, 32), tb, 0, stream>>>(ws_proj, wTps, 1024, 1024);
    transpose_k<<<dim3(96, 32), tb, 0, stream>>>(wt_qkv,  wTqt, 1024, 3072);
    transpose_k<<<dim3(32, 32), tb, 0, stream>>>(wt_proj, wTpt, 1024, 1024);

    // ---- spatial branch ----  (x1 fp32 lives in d_out)
    gemm_bt<<<dim3(24, 144), 256, 0, stream>>>(x_bf, wTqs, bs_qkv, nullptr,
                                               qkv, nullptr, TOK_, D3_, D_, 0);
    vtrans<<<dim3(9, 512), 256, 0, stream>>>(qkv, vt);
    attn_spatial<<<dim3(9, 512), 256, 0, stream>>>(qkv, vt, att);
    gemm_bt<<<dim3(8, 144), 256, 0, stream>>>(att, wTps, bs_proj, x,
                                              x1_bf, out, TOK_, D_, D_, 0);
    // ---- temporal branch ----  (qkv written in (b,hw,t) row order)
    gemm_bt<<<dim3(24, 144), 256, 0, stream>>>(x1_bf, wTqt, bt_qkv, nullptr,
                                               qkv, nullptr, TOK_, D3_, D_, 1);
    vtrans_t<<<1152, 256, 0, stream>>>(qkv, vtt);
    attn_temporal<<<1152, 256, 0, stream>>>(qkv, vtt, att);
    gemm_bt<<<dim3(8, 144), 256, 0, stream>>>(att, wTpt, bt_proj, out,
                                              nullptr, out, TOK_, D_, D_, 0);
}

// Round 5
// 870.472 us; speedup vs baseline: 4.6499x; 1.1767x over previous
//
#include <hip/hip_runtime.h>
#include <math.h>

typedef __bf16 bf16_t;
typedef __bf16 bf16x4 __attribute__((ext_vector_type(4)));
typedef __bf16 bf16x8 __attribute__((ext_vector_type(8)));
typedef float f32x4 __attribute__((ext_vector_type(4)));

#define GLDS(gp, lp) __builtin_amdgcn_global_load_lds( \
    (const __attribute__((address_space(1))) void*)(gp), \
    (__attribute__((address_space(3))) void*)(lp), 16, 0, 0)

static constexpr int B_    = 2;
static constexpr int T_    = 16;
static constexpr int HW_   = 576;
static constexpr int NH_   = 16;
static constexpr int TOK_  = B_ * T_ * HW_;   // 18432
static constexpr int D_    = 1024;
static constexpr int D3_   = 3072;

// ---------------------------------------------------------------------------
// fp32 -> bf16 elementwise convert (vectorized)
// ---------------------------------------------------------------------------
__global__ __launch_bounds__(256) void f2b(const float* __restrict__ in,
                                           bf16_t* __restrict__ out, long n)
{
    for (long i = ((long)blockIdx.x * 256 + threadIdx.x) * 4; i < n;
         i += (long)gridDim.x * 1024) {
        float4 v = *(const float4*)(in + i);
        bf16x4 o;
        o[0] = (bf16_t)v.x; o[1] = (bf16_t)v.y;
        o[2] = (bf16_t)v.z; o[3] = (bf16_t)v.w;
        *(bf16x4*)(out + i) = o;
    }
}

// ---------------------------------------------------------------------------
// Weight transpose + convert: out[N][K](bf16) = in[K][N](fp32), R=K, C=N
// ---------------------------------------------------------------------------
__global__ __launch_bounds__(256) void transpose_k(const float* __restrict__ in,
                                                   bf16_t* __restrict__ out,
                                                   int R, int C)
{
    __shared__ bf16_t tile[32][33];
    const int cb = blockIdx.x * 32, rb = blockIdx.y * 32;
    const int tx = threadIdx.x, ty = threadIdx.y;  // 32 x 8
    #pragma unroll
    for (int i = 0; i < 32; i += 8)
        tile[ty + i][tx] = (bf16_t)in[(long)(rb + ty + i) * C + cb + tx];
    __syncthreads();
    #pragma unroll
    for (int i = 0; i < 32; i += 8)
        out[(long)(cb + ty + i) * R + rb + tx] = tile[tx][ty + i];
}

// ---------------------------------------------------------------------------
// V transpose (spatial): vt[g=(bt*16+h)][d=64][hw=576]
// ---------------------------------------------------------------------------
__global__ __launch_bounds__(256) void vtrans(const bf16_t* __restrict__ qkv,
                                              bf16_t* __restrict__ vt)
{
    __shared__ bf16_t t[64][68];
    const int tid = threadIdx.x;
    const int hw0 = blockIdx.x * 64;          // 9 chunks
    const int g   = blockIdx.y;               // 512 groups
    const int bt  = g >> 4, h = g & 15;

    #pragma unroll
    for (int i = 0; i < 2; i++) {
        const int c = i * 256 + tid;          // 0..511
        const int row = c >> 3, di = (c & 7) * 8;
        *(bf16x8*)&t[row][di] =
            *(const bf16x8*)(qkv + ((long)bt * HW_ + hw0 + row) * D3_ + 2048 + h * 64 + di);
    }
    __syncthreads();
    #pragma unroll
    for (int i = 0; i < 2; i++) {
        const int c = i * 256 + tid;
        const int dd = c >> 3, hwl = (c & 7) * 8;
        bf16x8 v;
        #pragma unroll
        for (int jj = 0; jj < 8; jj++) v[jj] = t[hwl + jj][dd];
        *(bf16x8*)(vt + (long)g * (64 * 576) + (long)dd * 576 + hw0 + hwl) = v;
    }
}

// ---------------------------------------------------------------------------
// V transpose (temporal, from permuted qkv_t): vtt[g'=(bhw*16+h)][d=64][t=16]
// ---------------------------------------------------------------------------
__global__ __launch_bounds__(256) void vtrans_t(const bf16_t* __restrict__ qkv_t,
                                                bf16_t* __restrict__ vtt)
{
    __shared__ bf16_t tile[16][1026];
    const int tid = threadIdx.x;
    const long bhw = blockIdx.x;              // 0..1151
    #pragma unroll
    for (int it = 0; it < 8; it++) {
        const int c = it * 256 + tid;         // 0..2047 vec8 chunks
        const int row = c >> 7, col = (c & 127) * 8;
        *(bf16x8*)&tile[row][col] =
            *(const bf16x8*)(qkv_t + (bhw * 16 + row) * D3_ + 2048 + col);
    }
    __syncthreads();
    #pragma unroll
    for (int it = 0; it < 4; it++) {
        const int hd = it * 256 + tid;        // h*64+d, 0..1023
        bf16x8 v0, v1;
        #pragma unroll
        for (int t = 0; t < 8; t++) v0[t] = tile[t][hd];
        #pragma unroll
        for (int t = 0; t < 8; t++) v1[t] = tile[8 + t][hd];
        bf16_t* dst = vtt + (bhw * 16 + (hd >> 6)) * 1024 + (long)(hd & 63) * 16;
        *(bf16x8*)dst = v0;
        *(bf16x8*)(dst + 8) = v1;
    }
}

// ---------------------------------------------------------------------------
// GEMM: C = A[M][K](bf16) * BT[N][K](bf16)^T + bias[N](f32) (+ res[M][N](f32))
// outputs: Cb (bf16, optional) and/or Cf (f32, optional). fp32 accum.
// 128x128 tile, BK=32, 4 waves, 16x16x32 MFMA.
// 2-phase double-buffered staging (T3 minimum recipe): issue next tile's
// global_load_lds BEFORE computing current tile; ONE __syncthreads per
// K-step (its vmcnt(0)+lgkmcnt(0) drain is the phase boundary).
// tperm: store rows permuted (b,t,hw)->(b,hw,t) for the temporal branch.
// ---------------------------------------------------------------------------
__global__ __launch_bounds__(256) void gemm_bt(const bf16_t* __restrict__ A,
                                               const bf16_t* __restrict__ BT,
                                               const float* __restrict__ bias,
                                               const float* __restrict__ res,
                                               bf16_t* __restrict__ Cb,
                                               float* __restrict__ Cf,
                                               int M, int N, int K, int tperm)
{
    __shared__ bf16_t As[2][128 * 32];
    __shared__ bf16_t Bs[2][128 * 32];
    const int tid  = threadIdx.x;
    const int lane = tid & 63, wid = tid >> 6;
    const int wr   = wid >> 1, wc = wid & 1;
    const int l15  = lane & 15, lhi = lane >> 4;
    const long row0 = (long)blockIdx.y * 128;
    const long col0 = (long)blockIdx.x * 128;
    const int  sr   = tid >> 2;        // 0..63
    const int  sc   = (tid & 3) * 8;   // 0,8,16,24
    const bf16_t* Ag = A  + (row0 + sr) * (long)K + sc;
    const bf16_t* Bg = BT + (col0 + sr) * (long)K + sc;

    f32x4 acc[4][4] = {};

    // prologue: stage K-tile 0 into buffer 0
    GLDS(Ag,                &As[0][tid * 8]);
    GLDS(Ag + 64 * (long)K, &As[0][2048 + tid * 8]);
    GLDS(Bg,                &Bs[0][tid * 8]);
    GLDS(Bg + 64 * (long)K, &Bs[0][2048 + tid * 8]);
    __syncthreads();

    const int nt = K >> 5;
    int cur = 0;
    for (int t = 0; t < nt; ++t) {
        // stage t+1 into the other buffer (overlaps with compute below)
        if (t + 1 < nt) {
            const int k0 = (t + 1) << 5;
            GLDS(Ag + k0,                &As[cur ^ 1][tid * 8]);
            GLDS(Ag + 64 * (long)K + k0, &As[cur ^ 1][2048 + tid * 8]);
            GLDS(Bg + k0,                &Bs[cur ^ 1][tid * 8]);
            GLDS(Bg + 64 * (long)K + k0, &Bs[cur ^ 1][2048 + tid * 8]);
        }

        bf16x8 a[4], b[4];
        #pragma unroll
        for (int i = 0; i < 4; i++)
            a[i] = *(const bf16x8*)&As[cur][(wr * 64 + i * 16 + l15) * 32 + lhi * 8];
        #pragma unroll
        for (int j = 0; j < 4; j++)
            b[j] = *(const bf16x8*)&Bs[cur][(wc * 64 + j * 16 + l15) * 32 + lhi * 8];

        __builtin_amdgcn_s_setprio(1);
        #pragma unroll
        for (int i = 0; i < 4; i++)
            #pragma unroll
            for (int j = 0; j < 4; j++)
                acc[i][j] = __builtin_amdgcn_mfma_f32_16x16x32_bf16(a[i], b[j], acc[i][j], 0, 0, 0);
        __builtin_amdgcn_s_setprio(0);

        __syncthreads();   // drains vmcnt(0): next buffer staged; reads of cur done
        cur ^= 1;
    }

    // epilogue: C/D frag mapping col=lane&15, row=(lane>>4)*4+reg  [m89]
    #pragma unroll
    for (int i = 0; i < 4; i++) {
        #pragma unroll
        for (int j = 0; j < 4; j++) {
            #pragma unroll
            for (int r = 0; r < 4; r++) {
                const long row = row0 + wr * 64 + i * 16 + (lhi * 4 + r);
                const long col = col0 + wc * 64 + j * 16 + l15;
                long srow = row;
                if (tperm) {
                    const int ri  = (int)row;
                    const int bb  = ri / (T_ * HW_);
                    const int rem = ri - bb * (T_ * HW_);
                    const int tt  = rem / HW_;
                    const int hh  = rem - tt * HW_;
                    srow = ((long)bb * HW_ + hh) * T_ + tt;
                }
                float v = acc[i][j][r] + bias[col];
                if (res) v += res[row * (long)N + col];
                if (Cf)  Cf[srow * (long)N + col] = v;
                if (Cb)  Cb[srow * (long)N + col] = (bf16_t)v;
            }
        }
    }
}

// ---------------------------------------------------------------------------
// Spatial attention, MFMA flash-style (unchanged from R3).
// ---------------------------------------------------------------------------
__global__ __launch_bounds__(256) void attn_spatial(const bf16_t* __restrict__ qkv,
                                                    const bf16_t* __restrict__ vt,
                                                    bf16_t* __restrict__ out)
{
    __shared__ bf16_t Ks[64 * 64];
    __shared__ bf16_t Vts[64 * 64];
    __shared__ bf16_t Pws[4][16 * 72];
    const int tid = threadIdx.x, lane = tid & 63, w = tid >> 6;
    const int qt = blockIdx.x;            // 0..8
    const int g  = blockIdx.y;            // 0..511
    const int h  = g & 15, bt = g >> 4;
    const long base = (long)bt * HW_;
    const int l15 = lane & 15, lhi = lane >> 4;
    const int qrow0 = qt * 64 + w * 16;

    bf16x8 q[2];
    #pragma unroll
    for (int kk = 0; kk < 2; kk++)
        q[kk] = *(const bf16x8*)(qkv + (base + qrow0 + l15) * D3_ + h * 64 + kk * 32 + lhi * 8);

    const bf16_t* Kg = qkv + base * D3_ + 1024 + h * 64;
    const bf16_t* Vg = vt + (long)g * (64 * 576);

    float m[4], l[4];
    f32x4 o[4];
    #pragma unroll
    for (int r = 0; r < 4; r++) { m[r] = -INFINITY; l[r] = 0.f; }
    #pragma unroll
    for (int j = 0; j < 4; j++) o[j] = (f32x4){0.f, 0.f, 0.f, 0.f};

    for (int kt = 0; kt < 9; kt++) {
        __syncthreads();
        #pragma unroll
        for (int i = 0; i < 2; i++) {
            const int c = i * 256 + tid;
            const int r = c >> 3, cb = (c & 7) << 4;
            const int csrc = cb ^ ((r & 7) << 4);
            GLDS(Kg + (long)(kt * 64 + r) * D3_ + (csrc >> 1), (char*)Ks + c * 16);
            GLDS(Vg + (long)r * 576 + kt * 64 + (csrc >> 1), (char*)Vts + c * 16);
        }
        __syncthreads();

        f32x4 acc[4] = {};
        #pragma unroll
        for (int j = 0; j < 4; j++) {
            const int key = j * 16 + l15;
            #pragma unroll
            for (int kk = 0; kk < 2; kk++) {
                const int boff = key * 128 + ((kk * 64 + lhi * 16) ^ ((key & 7) << 4));
                bf16x8 kb = *(const bf16x8*)((const char*)Ks + boff);
                acc[j] = __builtin_amdgcn_mfma_f32_16x16x32_bf16(q[kk], kb, acc[j], 0, 0, 0);
            }
        }

        #pragma unroll
        for (int j = 0; j < 4; j++) acc[j] = acc[j] * 0.125f;
        #pragma unroll
        for (int r = 0; r < 4; r++) {
            float rm = fmaxf(fmaxf(acc[0][r], acc[1][r]), fmaxf(acc[2][r], acc[3][r]));
            #pragma unroll
            for (int off = 1; off < 16; off <<= 1) rm = fmaxf(rm, __shfl_xor(rm, off));
            const float mn = fmaxf(m[r], rm);
            const float sc = __expf(m[r] - mn);
            m[r] = mn;
            float rs = 0.f;
            #pragma unroll
            for (int j = 0; j < 4; j++) {
                const float p = __expf(acc[j][r] - mn);
                acc[j][r] = p;
                rs += p;
            }
            #pragma unroll
            for (int off = 1; off < 16; off <<= 1) rs += __shfl_xor(rs, off);
            l[r] = l[r] * sc + rs;
            #pragma unroll
            for (int j = 0; j < 4; j++) o[j][r] *= sc;
            #pragma unroll
            for (int j = 0; j < 4; j++)
                Pws[w][(lhi * 4 + r) * 72 + j * 16 + l15] = (bf16_t)acc[j][r];
        }
        __syncthreads();

        bf16x8 pa[2];
        #pragma unroll
        for (int kk = 0; kk < 2; kk++)
            pa[kk] = *(const bf16x8*)&Pws[w][l15 * 72 + kk * 32 + lhi * 8];
        #pragma unroll
        for (int j = 0; j < 4; j++) {
            const int vrow = j * 16 + l15;
            #pragma unroll
            for (int kk = 0; kk < 2; kk++) {
                const int boff = vrow * 128 + ((kk * 64 + lhi * 16) ^ ((vrow & 7) << 4));
                bf16x8 vb = *(const bf16x8*)((const char*)Vts + boff);
                o[j] = __builtin_amdgcn_mfma_f32_16x16x32_bf16(pa[kk], vb, o[j], 0, 0, 0);
            }
        }
    }

    #pragma unroll
    for (int r = 0; r < 4; r++) {
        const float inv = 1.f / l[r];
        const long row = base + qrow0 + lhi * 4 + r;
        #pragma unroll
        for (int j = 0; j < 4; j++)
            out[row * (long)D_ + h * 64 + j * 16 + l15] = (bf16_t)(o[j][r] * inv);
    }
}

// ---------------------------------------------------------------------------
// Temporal attention, MFMA (unchanged from R4).
// ---------------------------------------------------------------------------
__global__ __launch_bounds__(256) void attn_temporal(const bf16_t* __restrict__ qkv_t,
                                                     const bf16_t* __restrict__ vtt,
                                                     bf16_t* __restrict__ out)
{
    __shared__ bf16_t Plds[4][16 * 24];
    const int tid = threadIdx.x, lane = tid & 63, w = tid >> 6;
    const int l15 = lane & 15, lhi = lane >> 4;
    const int bhw = blockIdx.x;            // 0..1151
    const int b = bhw / HW_, hw = bhw % HW_;
    const long base_row = (long)bhw * T_;
    const bf16_t* qrow = qkv_t + (base_row + l15) * D3_;

    #pragma unroll
    for (int i = 0; i < 4; i++) {
        const int h = w * 4 + i;
        bf16x8 q0 = *(const bf16x8*)(qrow + h * 64 + lhi * 8);
        bf16x8 q1 = *(const bf16x8*)(qrow + h * 64 + 32 + lhi * 8);
        bf16x8 k0 = *(const bf16x8*)(qrow + 1024 + h * 64 + lhi * 8);
        bf16x8 k1 = *(const bf16x8*)(qrow + 1024 + h * 64 + 32 + lhi * 8);
        f32x4 acc = {};
        acc = __builtin_amdgcn_mfma_f32_16x16x32_bf16(q0, k0, acc, 0, 0, 0);
        acc = __builtin_amdgcn_mfma_f32_16x16x32_bf16(q1, k1, acc, 0, 0, 0);

        #pragma unroll
        for (int r = 0; r < 4; r++) {
            const int tq = lhi * 4 + r;
            float s = (l15 <= tq) ? acc[r] * 0.125f : -INFINITY;
            float mv = s;
            #pragma unroll
            for (int off = 1; off < 16; off <<= 1) mv = fmaxf(mv, __shfl_xor(mv, off));
            float p = __expf(s - mv);
            float sum = p;
            #pragma unroll
            for (int off = 1; off < 16; off <<= 1) sum += __shfl_xor(sum, off);
            Plds[w][tq * 24 + l15] = (bf16_t)(p / sum);
        }
        __builtin_amdgcn_sched_barrier(0);   // pin P-write before P-read

        bf16x8 pa = {};
        if (lhi < 2) pa = *(const bf16x8*)&Plds[w][l15 * 24 + lhi * 8];

        const bf16_t* vg = vtt + ((long)bhw * 16 + h) * 1024;
        #pragma unroll
        for (int j = 0; j < 4; j++) {
            bf16x8 vb = {};
            if (lhi < 2) vb = *(const bf16x8*)(vg + (long)(j * 16 + l15) * 16 + lhi * 8);
            f32x4 o = {};
            o = __builtin_amdgcn_mfma_f32_16x16x32_bf16(pa, vb, o, 0, 0, 0);
            #pragma unroll
            for (int r = 0; r < 4; r++) {
                const int tq = lhi * 4 + r;
                out[(((long)b * T_ + tq) * HW_ + hw) * D_ + h * 64 + j * 16 + l15] = (bf16_t)o[r];
            }
        }
        __builtin_amdgcn_sched_barrier(0);   // don't let next head's reads cross
    }
}

// ---------------------------------------------------------------------------
extern "C" void kernel_launch(void* const* d_in, const int* in_sizes, int n_in,
                              void* d_out, int out_size, void* d_ws, size_t ws_size,
                              hipStream_t stream)
{
    const float* x       = (const float*)d_in[0];
    const float* ws_qkv  = (const float*)d_in[1];
    const float* bs_qkv  = (const float*)d_in[2];
    const float* ws_proj = (const float*)d_in[3];
    const float* bs_proj = (const float*)d_in[4];
    const float* wt_qkv  = (const float*)d_in[5];
    const float* bt_qkv  = (const float*)d_in[6];
    const float* wt_proj = (const float*)d_in[7];
    const float* bt_proj = (const float*)d_in[8];
    float* out = (float*)d_out;
    (void)in_sizes; (void)n_in; (void)out_size;

    // workspace layout (bytes)
    char* ws = (char*)d_ws;
    bf16_t* qkv   = (bf16_t*)(ws);                  // 18432*3072*2 = 113,246,208
    bf16_t* x_bf  = (bf16_t*)(ws + 113246208L);     // 18432*1024*2 =  37,748,736
    bf16_t* att   = x_bf;                           // alias: att written after x_bf dead
    bf16_t* x1_bf = (bf16_t*)(ws + 150994944L);     //                 37,748,736
    bf16_t* vt    = x1_bf;                          // alias: vt dead before x1_bf written
    bf16_t* vtt   = x1_bf;                          // alias: vtt written after x1_bf dead
    bf16_t* wTqs  = (bf16_t*)(ws + 188743680L);     // 3072*1024*2 =    6,291,456
    bf16_t* wTps  = (bf16_t*)(ws + 195035136L);     // 1024*1024*2 =    2,097,152
    bf16_t* wTqt  = (bf16_t*)(ws + 197132288L);     //                  6,291,456
    bf16_t* wTpt  = (bf16_t*)(ws + 203423744L);     //                  2,097,152
    if (ws_size < 205520896UL) return;              // visible failure: out stays 0

    f2b<<<4096, 256, 0, stream>>>(x, x_bf, (long)TOK_ * D_);
    const dim3 tb(32, 8);
    transpose_k<<<dim3(96, 32), tb, 0, stream>>>(ws_qkv,  wTqs, 1024, 3072);
    transpose_k<<<dim3(32, 32), tb, 0, stream>>>(ws_proj, wTps, 1024, 1024);
    transpose_k<<<dim3(96, 32), tb, 0, stream>>>(wt_qkv,  wTqt, 1024, 3072);
    transpose_k<<<dim3(32, 32), tb, 0, stream>>>(wt_proj, wTpt, 1024, 1024);

    // ---- spatial branch ----  (x1 fp32 lives in d_out)
    gemm_bt<<<dim3(24, 144), 256, 0, stream>>>(x_bf, wTqs, bs_qkv, nullptr,
                                               qkv, nullptr, TOK_, D3_, D_, 0);
    vtrans<<<dim3(9, 512), 256, 0, stream>>>(qkv, vt);
    attn_spatial<<<dim3(9, 512), 256, 0, stream>>>(qkv, vt, att);
    gemm_bt<<<dim3(8, 144), 256, 0, stream>>>(att, wTps, bs_proj, x,
                                              x1_bf, out, TOK_, D_, D_, 0);
    // ---- temporal branch ----  (qkv written in (b,hw,t) row order)
    gemm_bt<<<dim3(24, 144), 256, 0, stream>>>(x1_bf, wTqt, bt_qkv, nullptr,
                                               qkv, nullptr, TOK_, D3_, D_, 1);
    vtrans_t<<<1152, 256, 0, stream>>>(qkv, vtt);
    attn_temporal<<<1152, 256, 0, stream>>>(qkv, vtt, att);
    gemm_bt<<<dim3(8, 144), 256, 0, stream>>>(att, wTpt, bt_proj, out,
                                              nullptr, out, TOK_, D_, D_, 0);
}